// Round 13
// baseline (165.716 us; speedup 1.0000x reference)
//
#include <hip/hip_runtime.h>
#include <math.h>

#define BATCH 8
#define NSEQ  4096
#define NWIN  65
#define OUTD  64
#define NB    21

typedef __attribute__((ext_vector_type(4))) float f32x4;
typedef __attribute__((ext_vector_type(4))) int   i32x4;
typedef __attribute__((ext_vector_type(8))) short bf16x8;

// f32 -> bf16 (round to nearest even), result in low 16 bits
static __device__ __forceinline__ unsigned int f2bf(float f) {
    unsigned int u = __builtin_bit_cast(unsigned int, f);
    u += 0x7fffu + ((u >> 16) & 1u);
    return u >> 16;
}

// out[b,o,w,s] = sum_n coefs[o,n] * basis[n](b,w,s)   (basis folds gain+scales)
// MFMA, SWAPPED operands vs R12: D(16 s x 16 o) = A(basis 16x32) * B(coefs 32x16).
// D layout (m89): col = o = lane&15, row = s = (lane>>4)*4 + reg  -> each lane
// holds 4 CONSECUTIVE s for one o-plane -> one NT dwordx4 store per tile
// (16 store instrs/lane, same as R11; 16x64B segments per wave-instr).
// Wave-private LDS basis transpose, 80B rows (throughput-optimal for b128),
// no block barriers.
__global__ __launch_bounds__(256, 4) void trf_kernel(
    const float* __restrict__ x,        // (8,1,4096)
    const float* __restrict__ conv_w,   // (3,1,2)
    const float* __restrict__ conv_b,   // (3,)
    const float* __restrict__ coefs,    // (64,1,21)
    float* __restrict__ out)            // (8,64,65,4096)
{
    const int tid  = threadIdx.x;
    const int lane = tid & 63;
    const int wid  = tid >> 6;
    const int blk  = blockIdx.x;
    const int og    = blk & 3;           // o = og*16 .. og*16+15
    const int chunk = (blk >> 2) & 3;    // 1024 s each
    const int bw    = blk >> 4;
    const int w     = bw % NWIN;
    const int b     = bw / NWIN;

    __shared__ int lds_i[4 * 128 * 20];  // 4 waves x 128 rows x 80B = 40960B

    // conv weights: wave-uniform scalar loads
    const float w00 = conv_w[0], w01 = conv_w[1];
    const float w10 = conv_w[2], w11 = conv_w[3];
    const float w20 = conv_w[4], w21 = conv_w[5];
    const float cb0 = conv_b[0], cb1 = conv_b[1], cb2 = conv_b[2];

    const float K      = 0.08055365778435367f;  // 2*pi/78
    const float SCALE  = 0.16012815380508713f;  // 1/sqrt(39)
    const float CONST0 = 0.11322770341445958f;  // 1/(sqrt(2)*sqrt(39))
    const float wl     = (float)(w + 7);

    const int col  = lane & 15;   // A row (s within tile) / B col (o) / D col (o)
    const int kseg = lane >> 4;   // k-slice; D row group = s-block

    // ---- B fragment: coefs[og*16+col][kseg*8 .. +8) as bf16, zero-pad k>=21
    unsigned int bu0, bu1, bu2, bu3;
    {
        const float* cr = coefs + (og * 16 + col) * NB;
        float f[8];
#pragma unroll
        for (int e = 0; e < 8; ++e) {
            const int k = kseg * 8 + e;
            f[e] = (k < NB) ? cr[k] : 0.0f;
        }
        bu0 = f2bf(f[0]) | (f2bf(f[1]) << 16);
        bu1 = f2bf(f[2]) | (f2bf(f[3]) << 16);
        bu2 = f2bf(f[4]) | (f2bf(f[5]) << 16);
        bu3 = f2bf(f[6]) | (f2bf(f[7]) << 16);
    }
    const bf16x8 bfrag = __builtin_bit_cast(bf16x8,
        (i32x4){(int)bu0, (int)bu1, (int)bu2, (int)bu3});

    const float* xb = x + (size_t)b * NSEQ;
    const int s_wave = chunk * 1024 + wid * 256;   // wave's s base

    // store base: lane's o-plane = og*16+col, s-block = kseg*4 (within 16-s tile)
    float* o_base = out
        + ((size_t)(b * OUTD + og * 16 + col) * NWIN + (size_t)w) * NSEQ
        + s_wave + kseg * 4;

    int* const lds_w = &lds_i[wid * (128 * 20)];   // wave-private region

#pragma unroll
    for (int h = 0; h < 2; ++h) {
        // WAR fence: this phase's LDS writes reuse rows read by previous phase
        asm volatile("s_waitcnt lgkmcnt(0)" ::: "memory");
        __builtin_amdgcn_sched_barrier(0);

        // ---- compute 2 points' basis, pack bf16, write LDS row (80B rows)
#pragma unroll
        for (int pp = 0; pp < 2; ++pp) {
            const int q     = lane + 64 * pp;       // phase-local row 0..127
            const int s_idx = s_wave + h * 128 + q; // 0..4095
            const float xc = xb[s_idx];
            const float xm = (s_idx > 0) ? xb[s_idx - 1] : 0.0f;

            const float p0 = fmaf(xm, w00, fmaf(xc, w01, cb0));
            const float p1 = fmaf(xm, w10, fmaf(xc, w11, cb1));
            const float p2 = fmaf(xm, w20, fmaf(xc, w21, cb2));
            const float a  = fabsf(p0);
            const float bs = fminf(fmaxf(p1, -7.0f), 7.0f);
            const float c  = fminf(fmaxf(1.0f + p2, 0.5f), 1.4f);

            const float theta = K * c * (wl - bs);
            float sn, cn;
            __sincosf(theta, &sn, &cn);

            float bas[NB];
            const float fa = a * SCALE;
            bas[0] = a * CONST0;
            const float twoc = 2.0f * cn;
            float sp = 0.0f, cp = 1.0f;
            float scur = sn, ccur = cn;
#pragma unroll
            for (int n = 1; n <= 10; ++n) {   // Chebyshev recurrence
                bas[2 * n - 1] = fa * scur;
                bas[2 * n]     = fa * ccur;
                const float snew = fmaf(twoc, scur, -sp);
                const float cnew = fmaf(twoc, ccur, -cp);
                sp = scur; cp = ccur; scur = snew; ccur = cnew;
            }

            unsigned int u[11];
#pragma unroll
            for (int i = 0; i < 10; ++i)
                u[i] = f2bf(bas[2 * i]) | (f2bf(bas[2 * i + 1]) << 16);
            u[10] = f2bf(bas[20]);              // k=21..31 zero

            int* row = lds_w + q * 20;
            *(i32x4*)(row)      = (i32x4){(int)u[0], (int)u[1], (int)u[2], (int)u[3]};
            *(i32x4*)(row + 4)  = (i32x4){(int)u[4], (int)u[5], (int)u[6], (int)u[7]};
            *(i32x4*)(row + 8)  = (i32x4){(int)u[8], (int)u[9], (int)u[10], 0};
            *(i32x4*)(row + 12) = (i32x4){0, 0, 0, 0};
        }

        // RAW fence: reads below consume rows written by OTHER lanes this phase
        asm volatile("s_waitcnt lgkmcnt(0)" ::: "memory");
        __builtin_amdgcn_sched_barrier(0);

        // ---- 8 tiles: A-frag (basis) from LDS, MFMA, ONE NT dwordx4 store
#pragma unroll
        for (int t = 0; t < 8; ++t) {
            const i32x4 ai = *(const i32x4*)(lds_w + (t * 16 + col) * 20 + kseg * 4);
            const bf16x8 afrag = __builtin_bit_cast(bf16x8, ai);
            const f32x4 d = __builtin_amdgcn_mfma_f32_16x16x32_bf16(
                afrag, bfrag, (f32x4){0.f, 0.f, 0.f, 0.f}, 0, 0, 0);
            // d[r] = out at s = s_wave + h*128 + t*16 + kseg*4 + r, o-plane og*16+col
            __builtin_nontemporal_store(d, (f32x4*)(o_base + h * 128 + t * 16));
        }
    }
}

extern "C" void kernel_launch(void* const* d_in, const int* in_sizes, int n_in,
                              void* d_out, int out_size, void* d_ws, size_t ws_size,
                              hipStream_t stream) {
    const float* x      = (const float*)d_in[0];
    const float* conv_w = (const float*)d_in[1];
    const float* conv_b = (const float*)d_in[2];
    const float* coefs  = (const float*)d_in[3];
    float* out = (float*)d_out;

    const int blocks = BATCH * NWIN * 4 /*s-chunks*/ * 4 /*o-groups*/;  // 8320
    trf_kernel<<<blocks, 256, 0, stream>>>(x, conv_w, conv_b, coefs, out);
}

// Round 14
// 98.787 us; speedup vs baseline: 1.6775x; 1.6775x over previous
//
#include <hip/hip_runtime.h>
#include <math.h>

#define BATCH 8
#define NSEQ  4096
#define NWIN  65
#define OUTD  64
#define NB    21

typedef __attribute__((ext_vector_type(4))) float f32x4;

// out[b,o,w,s] = a(b,s) * ( const0*coefs[o,0] + sum_{n=1..10} scale*(sin(n*th)*coefs[o,2n-1] + cos(n*th)*coefs[o,2n]) )
// th = (2*pi/78) * c(b,s) * ((w+7) - bshift(b,s))
// FINAL (R11 best, 95.7us): 8320 blocks (og fastest), 4 s-points x 16 outputs
// per thread, NT dwordx4 store issued inside the compute loop, 4 rotating
// accumulators -> VGPR < 128 -> 4 waves/SIMD. The block's 4 lock-step waves
// write the SAME 16 o-planes at adjacent s (4KB contiguous runs per plane);
// perturbing this (rotation/persistence/w-major/plain-stores/MFMA) all
// regressed (R7-R13). ~84% of fill-kernel write ceiling.
__global__ __launch_bounds__(256, 4) void trf_kernel(
    const float* __restrict__ x,        // (8,1,4096)
    const float* __restrict__ conv_w,   // (3,1,2)
    const float* __restrict__ conv_b,   // (3,)
    const float* __restrict__ coefs,    // (64,1,21)
    float* __restrict__ out)            // (8,64,65,4096)
{
    const int tid   = threadIdx.x;
    const int blk   = blockIdx.x;
    const int og    = blk & 3;           // output group: o = og*16 .. og*16+15
    const int chunk = (blk >> 2) & 3;    // 4 chunks of 1024 s each
    const int bw    = blk >> 4;
    const int w     = bw % NWIN;
    const int b     = bw / NWIN;
    const int s0    = chunk * 1024 + tid * 4;

    // conv weights: wave-uniform scalar loads
    const float w00 = conv_w[0], w01 = conv_w[1];
    const float w10 = conv_w[2], w11 = conv_w[3];
    const float w20 = conv_w[4], w21 = conv_w[5];
    const float cb0 = conv_b[0], cb1 = conv_b[1], cb2 = conv_b[2];

    const float* xb = x + (size_t)b * NSEQ;
    const f32x4 xq  = *(const f32x4*)(xb + s0);            // x[s0..s0+3], 16B aligned
    const float xm0 = (s0 > 0) ? xb[s0 - 1] : 0.0f;        // causal left-pad

    const float K      = 0.08055365778435367f;  // 2*pi/78
    const float SCALE  = 0.16012815380508713f;  // 1/sqrt(39)
    const float CONST0 = 0.11322770341445958f;  // 1/(sqrt(2)*sqrt(39))
    const float wl     = (float)(w + 7);

    f32x4 basis[NB];                                       // 84 VGPRs, static-indexed
#pragma unroll
    for (int p = 0; p < 4; ++p) {
        const float xm = (p == 0) ? xm0 : xq[p - 1];
        const float xc = xq[p];
        const float p0 = fmaf(xm, w00, fmaf(xc, w01, cb0));
        const float p1 = fmaf(xm, w10, fmaf(xc, w11, cb1));
        const float p2 = fmaf(xm, w20, fmaf(xc, w21, cb2));
        const float a  = fabsf(p0);
        const float bs = fminf(fmaxf(p1, -7.0f), 7.0f);
        const float c  = fminf(fmaxf(1.0f + p2, 0.5f), 1.4f);

        const float theta = K * c * (wl - bs);
        float sn, cn;
        __sincosf(theta, &sn, &cn);

        const float fa = a * SCALE;
        basis[0][p] = a * CONST0;
        const float twoc = 2.0f * cn;
        float sp = 0.0f, cp = 1.0f;      // sin(0), cos(0)
        float scur = sn, ccur = cn;      // sin(th), cos(th)
#pragma unroll
        for (int n = 1; n <= 10; ++n) {  // Chebyshev recurrence for sin/cos(n*th)
            basis[2 * n - 1][p] = fa * scur;
            basis[2 * n][p]     = fa * ccur;
            const float snew = fmaf(twoc, scur, -sp);
            const float cnew = fmaf(twoc, ccur, -cp);
            sp = scur; cp = ccur; scur = snew; ccur = cnew;
        }
    }

    // out index: ((b*64 + o)*65 + w)*4096 + s0
    float* op = out + ((size_t)(b * OUTD + og * 16) * NWIN + (size_t)w) * NSEQ + s0;
    const size_t ostride = (size_t)NWIN * NSEQ;

    const float* cwb = coefs + og * 16 * NB;   // uniform -> s_load batch
    f32x4 acc[4];                               // rotating accumulators
#pragma unroll
    for (int j = 0; j < 16; ++j) {
        const float* cw = cwb + j * NB;
        f32x4 a0 = basis[0] * cw[0];
#pragma unroll
        for (int n = 1; n < NB; ++n) {
            const float cs = cw[n];
            const f32x4 cv = {cs, cs, cs, cs};
            a0 = __builtin_elementwise_fma(basis[n], cv, a0);
        }
        acc[j & 3] = a0;
        // NT store issued inside compute loop (measured best, R6/R11)
        __builtin_nontemporal_store(acc[j & 3], (f32x4*)(op + (size_t)j * ostride));
    }
}

extern "C" void kernel_launch(void* const* d_in, const int* in_sizes, int n_in,
                              void* d_out, int out_size, void* d_ws, size_t ws_size,
                              hipStream_t stream) {
    const float* x      = (const float*)d_in[0];
    const float* conv_w = (const float*)d_in[1];
    const float* conv_b = (const float*)d_in[2];
    const float* coefs  = (const float*)d_in[3];
    float* out = (float*)d_out;

    const int blocks = BATCH * NWIN * 4 /*s-chunks*/ * 4 /*o-groups*/;  // 8320
    trf_kernel<<<blocks, 256, 0, stream>>>(x, conv_w, conv_b, coefs, out);
}